// Round 7
// baseline (299.678 us; speedup 1.0000x reference)
//
#include <hip/hip_runtime.h>
#include <cstdint>
#include <cstddef>

// ---------------------------------------------------------------------------
// CrossTransformer on MI355X.  B=4, N=2048, D=256, H=4, DH=64.
// R7: flash rewritten with ZERO LDS and ZERO barriers.
//   - S^T = K.Q^T via mfma_32x32x16 (A=K-frags from global dwordx4, B=Q^T in
//     regs); C-layout lane = one q-row => P^T B-frags built in registers with
//     16 packs + 8 ds_bpermute(l^32) per iter (no P round-trip through LDS).
//   - O^T = V^T.P^T; l via ones-A MFMA; epilogue packs to dwordx2 stores.
//   - No __syncthreads anywhere: compiler pipelines global loads across iters.
//   R6 diagnosis: R4 (16 waves/CU) and R6 (8 waves/CU) both 68.5us => the
//   barrier-serialized skeleton was the invariant, not occupancy/LDS BW.
// GEMMs/convs/lngelu unchanged from R6.
// ---------------------------------------------------------------------------

#define QKS2 0.4246609001440095f   // (DH^-0.25) * sqrt(log2(e))

typedef short bf16x8 __attribute__((ext_vector_type(8)));
typedef float f32x4  __attribute__((ext_vector_type(4)));
typedef float f32x16 __attribute__((ext_vector_type(16)));

__device__ __forceinline__ uint16_t f2bf(float f){
  union { float f; uint32_t u; } v; v.f = f;
  uint32_t r = v.u + 0x7FFFu + ((v.u >> 16) & 1u);
  return (uint16_t)(r >> 16);
}
__device__ __forceinline__ float bf2f(uint16_t h){
  union { uint32_t u; float f; } v; v.u = ((uint32_t)h) << 16; return v.f;
}
__device__ __forceinline__ uint32_t fbits(float f){
  union { float f; uint32_t u; } v; v.f = f; return v.u;
}
// pack two fp32 -> two bf16 (truncating): [lo16=trunc(a), hi16=trunc(b)]
__device__ __forceinline__ uint32_t pk2bf(float a, float b){
  return (fbits(b) & 0xFFFF0000u) | (fbits(a) >> 16);
}

// async global->LDS, 16B per lane; LDS dest = wave-uniform base + lane*16
__device__ __forceinline__ void gl_lds16(const void* g, void* l){
  void* g2 = const_cast<void*>(g);
  __builtin_amdgcn_global_load_lds((__attribute__((address_space(1))) void*)g2,
                                   (__attribute__((address_space(3))) void*)l,
                                   16, 0, 0);
}

// ---------------------------------------------------------------------------
// converts
// ---------------------------------------------------------------------------
__global__ __launch_bounds__(256) void conv_x_k(const float* __restrict__ x0,
                                                const float* __restrict__ x1,
                                                uint16_t* __restrict__ xb){
  const float* src = blockIdx.z ? x1 : x0;
  uint16_t* dst = xb + (size_t)blockIdx.z * 2097152;
  size_t i = ((size_t)blockIdx.x * 256 + threadIdx.x) * 4;
  float4 v = *(const float4*)(src + i);
  uint2 o;
  o.x = (uint32_t)f2bf(v.x) | ((uint32_t)f2bf(v.y) << 16);
  o.y = (uint32_t)f2bf(v.z) | ((uint32_t)f2bf(v.w) << 16);
  *(uint2*)(dst + i) = o;
}

// weights [K][N] fp32 -> transposed bf16 [N][K]
__global__ __launch_bounds__(256) void conv_w_k(
    const float* w0, const float* w1, const float* w2, const float* w3, const float* w4,
    uint16_t* t0, uint16_t* t1, uint16_t* t2, uint16_t* t3, uint16_t* t4){
  const int z = blockIdx.z;
  const float* src = z==0? w0 : z==1? w1 : z==2? w2 : z==3? w3 : w4;
  uint16_t*   dst  = z==0? t0 : z==1? t1 : z==2? t2 : z==3? t3 : t4;
  const int K = (z>=3)? 512 : 256;
  const int N = (z==3)? 512 : 256;
  int idx = blockIdx.x * 256 + threadIdx.x;
  if (idx >= (K*N)/4) return;
  int k = idx / (N/4);
  int n = (idx % (N/4)) * 4;
  float4 v = *(const float4*)(src + (size_t)k*N + n);
  dst[(size_t)(n+0)*K + k] = f2bf(v.x);
  dst[(size_t)(n+1)*K + k] = f2bf(v.y);
  dst[(size_t)(n+2)*K + k] = f2bf(v.z);
  dst[(size_t)(n+3)*K + k] = f2bf(v.w);
}

// ---------------------------------------------------------------------------
// unified GEMM  C[M=8192, N] = A[M,K](bf16) * W[K,N] + bias, epilogue by MODE
// Tile 64(M) x 128(N), BK=64.  4 waves, each 64x32 (acc 4x2).
// LDS tiles chunk-swizzled: (row r, 8-elem chunk c) at slot c^(r&7).
// ---------------------------------------------------------------------------
struct GemmArgs {
  const uint16_t* A0; const uint16_t* A1;
  const uint16_t* A2_0; const uint16_t* A2_1;
  const uint16_t* Wt0; const uint16_t* Wt1;
  const float* bias0; const float* bias1;
  uint16_t* out0; uint16_t* out1; uint16_t* out2; uint16_t* out3;
  float* fout; const float* xf0; const float* xf1;
  int K;
};

template<int MODE>
__global__ __launch_bounds__(256, 4) void gemm_k(GemmArgs a){
  __shared__ __align__(16) uint16_t As[64*64];
  __shared__ __align__(16) uint16_t Bs[128*64];
  const int tid = threadIdx.x;
  const int w = tid >> 6, l = tid & 63;
  const int z = blockIdx.z;
  const int which = (MODE==0) ? (z & 1) : z;
  const int wsel  = (MODE==0) ? (z >> 1) : 0;
  const int K = a.K;
  const int m0 = blockIdx.x * 64;
  const int n0 = blockIdx.y * 128;
  const uint16_t* Wt   = wsel ? a.Wt1 : a.Wt0;
  const float* bias    = wsel ? a.bias1 : a.bias0;
  const uint16_t* Ab   = which ? a.A1 : a.A0;
  const uint16_t* Ab2  = which ? a.A2_1 : a.A2_0;

  f32x4 acc[4][2];
  #pragma unroll
  for (int i=0;i<4;++i)
    #pragma unroll
    for (int j=0;j<2;++j) acc[i][j] = (f32x4){0.f,0.f,0.f,0.f};

  const int lrow8 = l >> 3, lch = l & 7;
  const int swch = (lch ^ lrow8) * 8;          // swizzled source chunk offset
  const int quad = l >> 4, l15 = l & 15, h7 = l15 & 7;

  for (int k0 = 0; k0 < K; k0 += 64){
    __syncthreads();
    const uint16_t* Asrc; int lda;
    if (MODE == 2){
      Asrc = (k0 < 256) ? (Ab + k0) : (Ab2 + (k0 - 256));
      lda = 256;
    } else { Asrc = Ab + k0; lda = K; }
    #pragma unroll
    for (int j=0;j<2;++j){
      int wi = w*2 + j;                    // 0..7
      int row = wi*8 + lrow8;              // 0..63
      gl_lds16(Asrc + (size_t)(m0 + row)*lda + swch, &As[wi*512]);
    }
    #pragma unroll
    for (int j=0;j<4;++j){
      int wi = w*4 + j;                    // 0..15
      int row = wi*8 + lrow8;              // 0..127
      gl_lds16(Wt + (size_t)(n0 + row)*K + k0 + swch, &Bs[wi*512]);
    }
    __syncthreads();
    #pragma unroll
    for (int kc=0;kc<2;++kc){
      const int fch = ((kc*4 + quad) ^ h7) * 8;  // swizzled fragment chunk
      bf16x8 af[4], bfr[2];
      #pragma unroll
      for (int rt=0;rt<4;++rt)
        af[rt] = *(const bf16x8*)&As[(rt*16 + l15)*64 + fch];
      #pragma unroll
      for (int ct=0;ct<2;++ct)
        bfr[ct] = *(const bf16x8*)&Bs[(w*32 + ct*16 + l15)*64 + fch];
      #pragma unroll
      for (int rt=0;rt<4;++rt)
        #pragma unroll
        for (int ct=0;ct<2;++ct)
          acc[rt][ct] = __builtin_amdgcn_mfma_f32_16x16x32_bf16(af[rt], bfr[ct], acc[rt][ct], 0,0,0);
    }
  }

  // epilogue (C layout: col = lane&15, row = (lane>>4)*4 + reg)
  #pragma unroll
  for (int rt=0;rt<4;++rt){
    const int r0 = m0 + rt*16 + (quad<<2);
    #pragma unroll
    for (int ct=0;ct<2;++ct){
      const int c = n0 + w*32 + ct*16 + l15;
      const float bv = bias[c];
      if (MODE == 0){
        if (wsel == 0){
          uint16_t* q = which ? a.out1 : a.out0;
          #pragma unroll
          for (int i=0;i<4;++i)
            q[(size_t)(r0+i)*256 + c] = f2bf((acc[rt][ct][i] + bv) * QKS2);
        } else {
          uint16_t* vt = which ? a.out3 : a.out2;
          const int bb = r0 >> 11, nn = r0 & 2047;
          const int hh = c >> 6,  dd = c & 63;
          uint2 pk;
          pk.x = (uint32_t)f2bf(acc[rt][ct][0] + bv) | ((uint32_t)f2bf(acc[rt][ct][1] + bv) << 16);
          pk.y = (uint32_t)f2bf(acc[rt][ct][2] + bv) | ((uint32_t)f2bf(acc[rt][ct][3] + bv) << 16);
          *(uint2*)(vt + ((size_t)((bb*4 + hh)*64 + dd))*2048 + nn) = pk;
        }
      } else if (MODE == 1){
        uint16_t* o = which ? a.out1 : a.out0;
        #pragma unroll
        for (int i=0;i<4;++i)
          o[(size_t)(r0+i)*256 + c] = f2bf(acc[rt][ct][i] + bv);
      } else if (MODE == 2){
        uint16_t* o = which ? a.out1 : a.out0;
        #pragma unroll
        for (int i=0;i<4;++i)
          o[(size_t)(r0+i)*512 + c] = f2bf(acc[rt][ct][i] + bv);
      } else {
        const float* xf = which ? a.xf1 : a.xf0;
        float* fo = a.fout + (size_t)which * 2097152;
        #pragma unroll
        for (int i=0;i<4;++i)
          fo[(size_t)(r0+i)*256 + c] = acc[rt][ct][i] + bv + xf[(size_t)(r0+i)*256 + c];
      }
    }
  }
}

// ---------------------------------------------------------------------------
// flash attention, no-LDS no-barrier version (32x32x16 MFMA).
// Block = 128 thr = 2 waves; wave handles 32 q-rows; grid (32,16,2).
// S^T = K.Q^T:  A-frag = K[key][d] (global dwordx4), B-frag = Q^T (regs).
//   C-layout: col = lane&31 = q-row, row = key = (reg&3)+8*(reg>>2)+4*(lane>>5).
// P^T B-frags built in registers: pack pairs + ds_bpermute with lane l^32
//   (partner shares lane&31 = same q-row; holds the other half of the keys).
// O^T = V^T.P^T; l = ones.P^T (all C rows equal).  No __syncthreads at all.
// ---------------------------------------------------------------------------
__global__ __launch_bounds__(128, 2) void flash_k(
    const uint16_t* __restrict__ qk0, const uint16_t* __restrict__ qk1,
    const uint16_t* __restrict__ vt0, const uint16_t* __restrict__ vt1,
    uint16_t* __restrict__ m0b, uint16_t* __restrict__ m1b){
  const int tid = threadIdx.x;
  const int w = tid >> 6, l = tid & 63;          // w in {0,1}
  const int l31 = l & 31, lhi = l >> 5;
  const int qt = blockIdx.x;       // 0..31
  const int bh = blockIdx.y;       // 0..15  (b*4 + h)
  const int dir = blockIdx.z;
  const int b = bh >> 2, h = bh & 3;
  const uint16_t* Q   = dir ? qk1 : qk0;
  const uint16_t* Kg  = dir ? qk0 : qk1;
  const uint16_t* Vt  = dir ? vt0 : vt1;
  uint16_t* outp      = dir ? m1b : m0b;

  const int qrow = b*2048 + qt*64 + w*32 + l31;  // this lane's q-row
  const int pidx = (l ^ 32) << 2;                // bpermute partner index
  const bool hi = (lhi != 0);

  const short ONE = (short)0x3F80;               // bf16 1.0
  const bf16x8 ones = {ONE,ONE,ONE,ONE,ONE,ONE,ONE,ONE};

  // Q^T B-frags: lane holds Q[qrow][d = ks*16 + lhi*8 + 0..7], ks=0..3
  bf16x8 qf[4];
  {
    const uint16_t* qp = Q + (size_t)qrow*256 + h*64 + lhi*8;
    #pragma unroll
    for (int ks=0;ks<4;++ks) qf[ks] = *(const bf16x8*)(qp + ks*16);
  }

  f32x16 o0, o1, lacc;
  #pragma unroll
  for (int i=0;i<16;++i){ o0[i]=0.f; o1[i]=0.f; lacc[i]=0.f; }

  // per-lane base pointers
  const uint16_t* Kbase = Kg + (size_t)(b*2048 + l31)*256 + h*64 + lhi*8;
  const uint16_t* Vbase = Vt + (size_t)bh*131072 + (size_t)l31*2048 + lhi*8;

  for (int kt=0; kt<32; ++kt){
    // ---- load K-frags (A: m=key) and V^T-frags (A: m=dout) ----
    bf16x8 kf[2][4], vf[2][4];
    #pragma unroll
    for (int kb=0;kb<2;++kb)
      #pragma unroll
      for (int ks=0;ks<4;++ks)
        kf[kb][ks] = *(const bf16x8*)(Kbase + (size_t)(kt*64 + kb*32)*256 + ks*16);
    #pragma unroll
    for (int db=0;db<2;++db)
      #pragma unroll
      for (int ks=0;ks<4;++ks)
        vf[db][ks] = *(const bf16x8*)(Vbase + (size_t)db*32*2048 + kt*64 + ks*16);

    // ---- S^T = K.Q^T : st0 keys 0..31, st1 keys 32..63 (local) ----
    f32x16 st0, st1;
    #pragma unroll
    for (int i=0;i<16;++i){ st0[i]=0.f; st1[i]=0.f; }
    #pragma unroll
    for (int ks=0;ks<4;++ks){
      st0 = __builtin_amdgcn_mfma_f32_32x32x16_bf16(kf[0][ks], qf[ks], st0, 0,0,0);
      st1 = __builtin_amdgcn_mfma_f32_32x32x16_bf16(kf[1][ks], qf[ks], st1, 0,0,0);
    }

    // ---- p = exp2(s); pack reg-quads as bf16 pairs ----
    // reg r holds key (r&3) + 8*(r>>2) + 4*lhi (local to 32-block)
    uint32_t pkA[2][4], pkB[2][4];     // [sblk][quad g]
    #pragma unroll
    for (int g=0; g<4; ++g){
      float a0 = __builtin_amdgcn_exp2f(st0[4*g+0]);
      float a1 = __builtin_amdgcn_exp2f(st0[4*g+1]);
      float a2 = __builtin_amdgcn_exp2f(st0[4*g+2]);
      float a3 = __builtin_amdgcn_exp2f(st0[4*g+3]);
      pkA[0][g] = pk2bf(a0, a1);
      pkB[0][g] = pk2bf(a2, a3);
      float c0 = __builtin_amdgcn_exp2f(st1[4*g+0]);
      float c1 = __builtin_amdgcn_exp2f(st1[4*g+1]);
      float c2 = __builtin_amdgcn_exp2f(st1[4*g+2]);
      float c3 = __builtin_amdgcn_exp2f(st1[4*g+3]);
      pkA[1][g] = pk2bf(c0, c1);
      pkB[1][g] = pk2bf(c2, c3);
    }

    // ---- build P^T B-frags via partner exchange (lane l^32) ----
    // frag f (keys f*16 + lhi*8 + i): sblk = f>>1, m2 = f&1; quad g_self = 2*m2+lhi.
    bf16x8 pfrag[4];
    #pragma unroll
    for (int f=0; f<4; ++f){
      const int sb = f >> 1, m2 = f & 1;
      uint32_t ownA0 = pkA[sb][2*m2],   ownB0 = pkB[sb][2*m2];    // quad 2m2
      uint32_t ownA1 = pkA[sb][2*m2+1], ownB1 = pkB[sb][2*m2+1];  // quad 2m2+1
      // send partner what it needs (its g = 2m2 + partner_lhi)
      uint32_t tA = hi ? ownA0 : ownA1;
      uint32_t tB = hi ? ownB0 : ownB1;
      uint32_t rA = (uint32_t)__builtin_amdgcn_ds_bpermute(pidx, (int)tA);
      uint32_t rB = (uint32_t)__builtin_amdgcn_ds_bpermute(pidx, (int)tB);
      // assemble: i0-3 from lhi_h=0 holder, i4-7 from lhi_h=1 holder (quad g_self)
      uint32_t v0 = hi ? rA : ownA0;
      uint32_t v1 = hi ? rB : ownB0;
      uint32_t v2 = hi ? ownA1 : rA;
      uint32_t v3 = hi ? ownB1 : rB;
      union { uint32_t u[4]; bf16x8 v; } cvt;
      cvt.u[0]=v0; cvt.u[1]=v1; cvt.u[2]=v2; cvt.u[3]=v3;
      pfrag[f] = cvt.v;
    }

    // ---- l += ones.P^T ; O^T += V^T.P^T ----
    #pragma unroll
    for (int f=0; f<4; ++f)
      lacc = __builtin_amdgcn_mfma_f32_32x32x16_bf16(ones, pfrag[f], lacc, 0,0,0);
    #pragma unroll
    for (int f=0; f<4; ++f){
      o0 = __builtin_amdgcn_mfma_f32_32x32x16_bf16(vf[0][f], pfrag[f], o0, 0,0,0);
      o1 = __builtin_amdgcn_mfma_f32_32x32x16_bf16(vf[1][f], pfrag[f], o1, 0,0,0);
    }
  }

  // ---- epilogue: lane owns q-row l31; O^T col = l31, row = dout ----
  const float inv = 1.0f / lacc[0];   // all lacc rows equal (ones-A)
  uint16_t* op = outp + (size_t)qrow*256 + h*64 + lhi*4;
  #pragma unroll
  for (int g=0; g<4; ++g){
    // o0 quad g: douts 8g+4lhi+0..3 ; o1: +32
    uint32_t p01 = (uint32_t)f2bf(o0[4*g+0]*inv) | ((uint32_t)f2bf(o0[4*g+1]*inv) << 16);
    uint32_t p23 = (uint32_t)f2bf(o0[4*g+2]*inv) | ((uint32_t)f2bf(o0[4*g+3]*inv) << 16);
    *(uint2*)(op + 8*g) = (uint2){p01, p23};
    uint32_t q01 = (uint32_t)f2bf(o1[4*g+0]*inv) | ((uint32_t)f2bf(o1[4*g+1]*inv) << 16);
    uint32_t q23 = (uint32_t)f2bf(o1[4*g+2]*inv) | ((uint32_t)f2bf(o1[4*g+3]*inv) << 16);
    *(uint2*)(op + 32 + 8*g) = (uint2){q01, q23};
  }
}

// ---------------------------------------------------------------------------
// LayerNorm + exact GELU, one wave per 512-wide row, bf16 in/out
// ---------------------------------------------------------------------------
__global__ __launch_bounds__(256) void lngelu_k(const uint16_t* __restrict__ hpre,
                                                const float* __restrict__ g,
                                                const float* __restrict__ bb,
                                                uint16_t* __restrict__ h){
  const int row = blockIdx.x*4 + (threadIdx.x >> 6);
  const int l = threadIdx.x & 63;
  const uint16_t* rp = hpre + (size_t)row*512 + l*8;
  uint4 raw = *(const uint4*)rp;
  uint32_t wv[4] = {raw.x, raw.y, raw.z, raw.w};
  float x[8];
  #pragma unroll
  for (int j=0;j<4;++j){
    x[2*j]   = bf2f((uint16_t)(wv[j] & 0xFFFFu));
    x[2*j+1] = bf2f((uint16_t)(wv[j] >> 16));
  }
  float s = 0.f;
  #pragma unroll
  for (int j=0;j<8;++j) s += x[j];
  #pragma unroll
  for (int off=1; off<64; off<<=1) s += __shfl_xor(s, off, 64);
  float mu = s * (1.0f/512.0f);
  float vs = 0.f;
  #pragma unroll
  for (int j=0;j<8;++j){ float d = x[j]-mu; vs += d*d; }
  #pragma unroll
  for (int off=1; off<64; off<<=1) vs += __shfl_xor(vs, off, 64);
  float rstd = rsqrtf(vs*(1.0f/512.0f) + 1e-5f);
  const float* gp = g + l*8;
  const float* bp = bb + l*8;
  uint32_t ow[4];
  #pragma unroll
  for (int j=0;j<4;++j){
    float y0 = (x[2*j]-mu)*rstd*gp[2*j] + bp[2*j];
    float y1 = (x[2*j+1]-mu)*rstd*gp[2*j+1] + bp[2*j+1];
    float g0 = 0.5f*y0*(1.0f + erff(y0*0.70710678118f));
    float g1 = 0.5f*y1*(1.0f + erff(y1*0.70710678118f));
    ow[j] = (uint32_t)f2bf(g0) | ((uint32_t)f2bf(g1) << 16);
  }
  uint4 out4 = {ow[0], ow[1], ow[2], ow[3]};
  *(uint4*)(h + (size_t)row*512 + l*8) = out4;
}

// ---------------------------------------------------------------------------
extern "C" void kernel_launch(void* const* d_in, const int* in_sizes, int n_in,
                              void* d_out, int out_size, void* d_ws, size_t ws_size,
                              hipStream_t stream){
  (void)in_sizes; (void)n_in; (void)out_size; (void)ws_size;
  const float* x0   = (const float*)d_in[0];
  const float* x1   = (const float*)d_in[1];
  const float* w_qk = (const float*)d_in[2];
  const float* b_qk = (const float*)d_in[3];
  const float* w_v  = (const float*)d_in[4];
  const float* b_v  = (const float*)d_in[5];
  const float* w_out= (const float*)d_in[6];
  const float* b_out= (const float*)d_in[7];
  const float* w_f1 = (const float*)d_in[8];
  const float* b_f1 = (const float*)d_in[9];
  const float* ln_g = (const float*)d_in[10];
  const float* ln_b = (const float*)d_in[11];
  const float* w_f2 = (const float*)d_in[12];
  const float* b_f2 = (const float*)d_in[13];

  char* ws = (char*)d_ws;
  uint16_t* xb    = (uint16_t*)(ws);              //  8,388,608 B  [x0b | x1b]
  uint16_t* wqkT  = (uint16_t*)(ws +  8388608);
  uint16_t* wvT   = (uint16_t*)(ws +  8519680);
  uint16_t* woutT = (uint16_t*)(ws +  8650752);
  uint16_t* wf1T  = (uint16_t*)(ws +  8781824);
  uint16_t* wf2T  = (uint16_t*)(ws +  9306112);
  uint16_t* qk0b  = (uint16_t*)(ws +  9568256);
  uint16_t* qk1b  = (uint16_t*)(ws + 13762560);
  uint16_t* vt0b  = (uint16_t*)(ws + 17956864);
  uint16_t* vt1b  = (uint16_t*)(ws + 22151168);
  uint16_t* m0b   = (uint16_t*)(ws + 26345472);
  uint16_t* m1b   = (uint16_t*)(ws + 30539776);
  uint16_t* mp0b  = (uint16_t*)(ws + 34734080);
  uint16_t* mp1b  = (uint16_t*)(ws + 38928384);
  // aliases over dead buffers:
  uint16_t* hpreb = qk0b;   // [2][8192][512] bf16 over qk0..vt1 (dead after flash)
  uint16_t* hb    = m0b;    // [2][8192][512] bf16 over m0..mp1 (dead after ffn1)

  conv_x_k<<<dim3(2048,1,2), 256, 0, stream>>>(x0, x1, xb);
  conv_w_k<<<dim3(256,1,5), 256, 0, stream>>>(w_qk, w_v, w_out, w_f1, w_f2,
                                              wqkT, wvT, woutT, wf1T, wf2T);

  GemmArgs g0 = {};
  g0.A0 = xb; g0.A1 = xb + 2097152;
  g0.Wt0 = wqkT; g0.Wt1 = wvT;
  g0.bias0 = b_qk; g0.bias1 = b_v;
  g0.out0 = qk0b; g0.out1 = qk1b; g0.out2 = vt0b; g0.out3 = vt1b;
  g0.K = 256;
  gemm_k<0><<<dim3(128,2,4), 256, 0, stream>>>(g0);

  flash_k<<<dim3(32,16,2), 128, 0, stream>>>(qk0b, qk1b, vt0b, vt1b, m0b, m1b);

  GemmArgs g1 = {};
  g1.A0 = m0b; g1.A1 = m1b;
  g1.Wt0 = woutT; g1.bias0 = b_out;
  g1.out0 = mp0b; g1.out1 = mp1b;
  g1.K = 256;
  gemm_k<1><<<dim3(128,2,2), 256, 0, stream>>>(g1);

  GemmArgs g2 = {};
  g2.A0 = xb; g2.A1 = xb + 2097152;
  g2.A2_0 = mp0b; g2.A2_1 = mp1b;
  g2.Wt0 = wf1T; g2.bias0 = b_f1;
  g2.out0 = hpreb; g2.out1 = hpreb + 4194304;
  g2.K = 512;
  gemm_k<2><<<dim3(128,4,2), 256, 0, stream>>>(g2);

  lngelu_k<<<dim3(4096,1,1), 256, 0, stream>>>(hpreb, ln_g, ln_b, hb);

  GemmArgs g3 = {};
  g3.A0 = hb; g3.A1 = hb + 4194304;
  g3.Wt0 = wf2T; g3.bias0 = b_f2;
  g3.fout = (float*)d_out;
  g3.xf0 = x0; g3.xf1 = x1;
  g3.K = 512;
  gemm_k<3><<<dim3(128,2,2), 256, 0, stream>>>(g3);
}

// Round 8
// 248.125 us; speedup vs baseline: 1.2078x; 1.2078x over previous
//
#include <hip/hip_runtime.h>
#include <cstdint>
#include <cstddef>

// ---------------------------------------------------------------------------
// CrossTransformer on MI355X.  B=4, N=2048, D=256, H=4, DH=64.
// R8: discriminating experiment on the 68.5us flash wall (drain-count vs
//     staged-bytes).  Flash = R6 32x32 structure with K-tile 128: same bytes,
//     same MFMA, HALF the vmcnt(0)+barrier drains (16 vs 32).
//     GEMMs: BK=128 (2-4 K-iters, 48KB LDS, 3 blocks/CU).  Converts merged.
//     Unified swizzle for 16-chunk rows: slot = chunk ^ (row & 15);
//     8-chunk rows keep slot = c ^ (r&7) ^ ((r>>3)&7)  [R6-verified].
// R7 lesson: per-lane global gathers (64 lines/instr) >> staged loads; revert.
// ---------------------------------------------------------------------------

#define QKS2 0.4246609001440095f   // (DH^-0.25) * sqrt(log2(e))

typedef short bf16x8 __attribute__((ext_vector_type(8)));
typedef float f32x4  __attribute__((ext_vector_type(4)));
typedef float f32x16 __attribute__((ext_vector_type(16)));

__device__ __forceinline__ uint16_t f2bf(float f){
  union { float f; uint32_t u; } v; v.f = f;
  uint32_t r = v.u + 0x7FFFu + ((v.u >> 16) & 1u);
  return (uint16_t)(r >> 16);
}
__device__ __forceinline__ uint16_t f2bf_trunc(float f){
  union { float f; uint32_t u; } v; v.f = f;
  return (uint16_t)(v.u >> 16);
}
__device__ __forceinline__ float bf2f(uint16_t h){
  union { uint32_t u; float f; } v; v.u = ((uint32_t)h) << 16; return v.f;
}

// async global->LDS, 16B per lane; LDS dest = wave-uniform base + lane*16
__device__ __forceinline__ void gl_lds16(const void* g, void* l){
  void* g2 = const_cast<void*>(g);
  __builtin_amdgcn_global_load_lds((__attribute__((address_space(1))) void*)g2,
                                   (__attribute__((address_space(3))) void*)l,
                                   16, 0, 0);
}

// ---------------------------------------------------------------------------
// merged converts: z=0..4 -> weights [K][N] fp32 -> bf16 [N][K]; z=5,6 -> x
// ---------------------------------------------------------------------------
__global__ __launch_bounds__(256) void conv_all_k(
    const float* __restrict__ x0, const float* __restrict__ x1,
    uint16_t* __restrict__ xb,
    const float* w0, const float* w1, const float* w2, const float* w3, const float* w4,
    uint16_t* t0, uint16_t* t1, uint16_t* t2, uint16_t* t3, uint16_t* t4){
  const int z = blockIdx.z;
  if (z >= 5){
    const float* src = (z == 6) ? x1 : x0;
    uint16_t* dst = xb + (size_t)(z - 5) * 2097152;
    size_t i = ((size_t)blockIdx.x * 256 + threadIdx.x) * 4;
    float4 v = *(const float4*)(src + i);
    uint2 o;
    o.x = (uint32_t)f2bf(v.x) | ((uint32_t)f2bf(v.y) << 16);
    o.y = (uint32_t)f2bf(v.z) | ((uint32_t)f2bf(v.w) << 16);
    *(uint2*)(dst + i) = o;
    return;
  }
  const float* src = z==0? w0 : z==1? w1 : z==2? w2 : z==3? w3 : w4;
  uint16_t*   dst  = z==0? t0 : z==1? t1 : z==2? t2 : z==3? t3 : t4;
  const int K = (z>=3)? 512 : 256;
  const int N = (z==3)? 512 : 256;
  int idx = blockIdx.x * 256 + threadIdx.x;
  if (idx >= (K*N)/4) return;
  int k = idx / (N/4);
  int n = (idx % (N/4)) * 4;
  float4 v = *(const float4*)(src + (size_t)k*N + n);
  dst[(size_t)(n+0)*K + k] = f2bf(v.x);
  dst[(size_t)(n+1)*K + k] = f2bf(v.y);
  dst[(size_t)(n+2)*K + k] = f2bf(v.z);
  dst[(size_t)(n+3)*K + k] = f2bf(v.w);
}

// ---------------------------------------------------------------------------
// unified GEMM  C[M=8192, N] = A[M,K](bf16) * W[K,N] + bias, epilogue by MODE
// Tile 64(M) x 128(N), BK=128.  4 waves, each 64x32 (acc 4x2).
// 16-chunk rows, swizzle slot = c ^ (r & 15).
// ---------------------------------------------------------------------------
struct GemmArgs {
  const uint16_t* A0; const uint16_t* A1;
  const uint16_t* A2_0; const uint16_t* A2_1;
  const uint16_t* Wt0; const uint16_t* Wt1;
  const float* bias0; const float* bias1;
  uint16_t* out0; uint16_t* out1; uint16_t* out2; uint16_t* out3;
  float* fout; const float* xf0; const float* xf1;
  int K;
};

template<int MODE>
__global__ __launch_bounds__(256, 3) void gemm_k(GemmArgs a){
  __shared__ __align__(16) uint16_t As[64*128];    // 16 KB
  __shared__ __align__(16) uint16_t Bs[128*128];   // 32 KB
  const int tid = threadIdx.x;
  const int w = tid >> 6, l = tid & 63;
  const int z = blockIdx.z;
  const int which = (MODE==0) ? (z & 1) : z;
  const int wsel  = (MODE==0) ? (z >> 1) : 0;
  const int K = a.K;
  const int m0 = blockIdx.x * 64;
  const int n0 = blockIdx.y * 128;
  const uint16_t* Wt   = wsel ? a.Wt1 : a.Wt0;
  const float* bias    = wsel ? a.bias1 : a.bias0;
  const uint16_t* Ab   = which ? a.A1 : a.A0;
  const uint16_t* Ab2  = which ? a.A2_1 : a.A2_0;

  f32x4 acc[4][2];
  #pragma unroll
  for (int i=0;i<4;++i)
    #pragma unroll
    for (int j=0;j<2;++j) acc[i][j] = (f32x4){0.f,0.f,0.f,0.f};

  const int lrow16 = l >> 4, lch16 = l & 15;
  const int quad = l >> 4, l15 = l & 15;

  for (int k0 = 0; k0 < K; k0 += 128){
    __syncthreads();
    const uint16_t* Asrc; int lda;
    if (MODE == 2){
      Asrc = (k0 < 256) ? (Ab + k0) : (Ab2 + (k0 - 256));
      lda = 256;
    } else { Asrc = Ab + k0; lda = K; }
    #pragma unroll
    for (int j=0;j<4;++j){
      int g = w*4 + j;                       // 0..15
      int row = g*4 + lrow16;                // 0..63
      int sc = lch16 ^ (row & 15);
      gl_lds16(Asrc + (size_t)(m0 + row)*lda + sc*8, &As[g*512]);
    }
    #pragma unroll
    for (int j=0;j<8;++j){
      int g = w*8 + j;                       // 0..31
      int row = g*4 + lrow16;                // 0..127
      int sc = lch16 ^ (row & 15);
      gl_lds16(Wt + (size_t)(n0 + row)*K + k0 + sc*8, &Bs[g*512]);
    }
    __syncthreads();
    #pragma unroll
    for (int kc=0;kc<4;++kc){
      const int ch = kc*4 + quad;            // k-chunk 0..15
      bf16x8 af[4], bfr[2];
      #pragma unroll
      for (int rt=0;rt<4;++rt)
        af[rt] = *(const bf16x8*)&As[(rt*16 + l15)*128 + (ch ^ l15)*8];
      #pragma unroll
      for (int ct=0;ct<2;++ct)
        bfr[ct] = *(const bf16x8*)&Bs[(w*32 + ct*16 + l15)*128 + (ch ^ l15)*8];
      #pragma unroll
      for (int rt=0;rt<4;++rt)
        #pragma unroll
        for (int ct=0;ct<2;++ct)
          acc[rt][ct] = __builtin_amdgcn_mfma_f32_16x16x32_bf16(af[rt], bfr[ct], acc[rt][ct], 0,0,0);
    }
  }

  // epilogue (C layout: col = lane&15, row = (lane>>4)*4 + reg)
  #pragma unroll
  for (int rt=0;rt<4;++rt){
    const int r0 = m0 + rt*16 + (quad<<2);
    #pragma unroll
    for (int ct=0;ct<2;++ct){
      const int c = n0 + w*32 + ct*16 + l15;
      const float bv = bias[c];
      if (MODE == 0){
        if (wsel == 0){
          uint16_t* q = which ? a.out1 : a.out0;
          #pragma unroll
          for (int i=0;i<4;++i)
            q[(size_t)(r0+i)*256 + c] = f2bf((acc[rt][ct][i] + bv) * QKS2);
        } else {
          uint16_t* vt = which ? a.out3 : a.out2;
          const int bb = r0 >> 11, nn = r0 & 2047;
          const int hh = c >> 6,  dd = c & 63;
          uint2 pk;
          pk.x = (uint32_t)f2bf(acc[rt][ct][0] + bv) | ((uint32_t)f2bf(acc[rt][ct][1] + bv) << 16);
          pk.y = (uint32_t)f2bf(acc[rt][ct][2] + bv) | ((uint32_t)f2bf(acc[rt][ct][3] + bv) << 16);
          *(uint2*)(vt + ((size_t)((bb*4 + hh)*64 + dd))*2048 + nn) = pk;
        }
      } else if (MODE == 1){
        uint16_t* o = which ? a.out1 : a.out0;
        #pragma unroll
        for (int i=0;i<4;++i)
          o[(size_t)(r0+i)*256 + c] = f2bf(acc[rt][ct][i] + bv);
      } else if (MODE == 2){
        uint16_t* o = which ? a.out1 : a.out0;
        #pragma unroll
        for (int i=0;i<4;++i)
          o[(size_t)(r0+i)*512 + c] = f2bf(acc[rt][ct][i] + bv);
      } else {
        const float* xf = which ? a.xf1 : a.xf0;
        float* fo = a.fout + (size_t)which * 2097152;
        #pragma unroll
        for (int i=0;i<4;++i)
          fo[(size_t)(r0+i)*256 + c] = acc[rt][ct][i] + bv + xf[(size_t)(r0+i)*256 + c];
      }
    }
  }
}

// ---------------------------------------------------------------------------
// flash attention, 32x32x16 MFMA, K-tile 128 (16 iterations of the K loop).
// Q tile 64 = 2 waves x 32 q-rows; grid (32,16,2), 128 thr.
// Same staged bytes and MFMA count as R6, HALF the barrier drains.
// Ks: [key 0..127][d 0..63]  8-chunk rows, swz = c^(r&7)^((r>>3)&7)
// Vs: [dout 0..63][key 0..127] 16-chunk rows, swz = c^(r&15)
// Ps: [qrow 0..63][key 0..127] 16-chunk rows, swz = c^(r&15); Q staged here
//     first in 8-chunk-row format (consumed into regs before P writes).
// LDS 48KB -> 3 blocks/CU.
// ---------------------------------------------------------------------------
__global__ __launch_bounds__(128, 2) void flash_k(
    const uint16_t* __restrict__ qk0, const uint16_t* __restrict__ qk1,
    const uint16_t* __restrict__ vt0, const uint16_t* __restrict__ vt1,
    uint16_t* __restrict__ m0b, uint16_t* __restrict__ m1b){
  __shared__ __align__(16) uint16_t Ks[128*64];
  __shared__ __align__(16) uint16_t Vs[64*128];
  __shared__ __align__(16) uint16_t Ps[64*128];
  const int tid = threadIdx.x;
  const int w = tid >> 6, l = tid & 63;          // w in {0,1}
  const int l31 = l & 31, lhi = l >> 5;
  const int rsub = l31 >> 3;
  const int qt = blockIdx.x;       // 0..31
  const int bh = blockIdx.y;       // 0..15  (b*4 + h)
  const int dir = blockIdx.z;
  const int b = bh >> 2, h = bh & 3;
  const uint16_t* Q   = dir ? qk1 : qk0;
  const uint16_t* Kg  = dir ? qk0 : qk1;
  const uint16_t* Vt  = dir ? vt0 : vt1;
  uint16_t* outp      = dir ? m1b : m0b;

  const int qrow0 = b*2048 + qt*64;
  const int lrow8 = l >> 3, lch8 = l & 7;
  const int lrow16 = l >> 4, lch16 = l & 15;

  const short ONE = (short)0x3F80;               // bf16 1.0
  const bf16x8 ones = {ONE,ONE,ONE,ONE,ONE,ONE,ONE,ONE};

  // ---- stage Q (64 rows x 64 d) into Ps, 8-chunk-row format ----
  #pragma unroll
  for (int j=0;j<4;++j){
    int g = w*4 + j;                             // 0..7
    int row = g*8 + lrow8;                       // 0..63
    int sc = lch8 ^ lrow8 ^ (g & 7);
    gl_lds16(Q + (size_t)(qrow0 + row)*256 + h*64 + sc*8, &Ps[g*512]);
  }
  __syncthreads();
  bf16x8 qf[4];
  {
    const int qmask = (l & 7) ^ ((w*4 + rsub) & 7);   // row = w*32 + l31
    #pragma unroll
    for (int ks=0;ks<4;++ks)
      qf[ks] = *(const bf16x8*)&Ps[(w*32 + l31)*64 + (((ks*2 + lhi) ^ qmask))*8];
  }

  f32x16 o0, o1, lacc;
  #pragma unroll
  for (int i=0;i<16;++i){ o0[i]=0.f; o1[i]=0.f; lacc[i]=0.f; }

  const size_t vbase = (size_t)bh * 131072;      // 64*2048
  const int pm15 = l31 & 15;                     // read-mask for Ps/Vs rows (w*32|db*32 drop out)

  for (int kt=0; kt<16; ++kt){
    __syncthreads();   // prior-iter LDS readers done; protects qf/Ps alias on iter 0
    #pragma unroll
    for (int j=0;j<8;++j){
      int g = w*8 + j;                           // 0..15
      int rowk = g*8 + lrow8;                    // 0..127
      int sck = lch8 ^ lrow8 ^ (g & 7);
      gl_lds16(Kg + (size_t)(b*2048 + kt*128 + rowk)*256 + h*64 + sck*8, &Ks[g*512]);
      int rowv = g*4 + lrow16;                   // 0..63
      int scv = lch16 ^ (rowv & 15);
      gl_lds16(Vt + vbase + (size_t)rowv*2048 + kt*128 + scv*8, &Vs[g*1024]);
    }
    __syncthreads();

    // ---- S = Q K^T per 32-key block; p = exp2(s); write P ----
    #pragma unroll
    for (int kb=0;kb<4;++kb){
      const int kmask = (l31 & 7) ^ ((kb*4 + rsub) & 7);
      f32x16 st;
      #pragma unroll
      for (int i=0;i<16;++i) st[i]=0.f;
      #pragma unroll
      for (int ks=0;ks<4;++ks){
        bf16x8 kf = *(const bf16x8*)&Ks[(kb*32 + l31)*64 + (((ks*2 + lhi) ^ kmask))*8];
        st = __builtin_amdgcn_mfma_f32_32x32x16_bf16(qf[ks], kf, st, 0,0,0);
      }
      const int kc = kb*4 + rsub;                // key chunk 0..15
      #pragma unroll
      for (int reg=0; reg<16; ++reg){
        int qrm  = (reg&3) + 8*(reg>>2) + 4*lhi; // 0..31
        int prow = w*32 + qrm;
        int slot = kc ^ (qrm & 15);              // prow&15 == qrm&15
        float p = __builtin_amdgcn_exp2f(st[reg]);
        Ps[prow*128 + slot*8 + (l31 & 7)] = f2bf_trunc(p);
      }
    }

    // ---- l += P.ones ; O += P.V  (P rows wave-private) ----
    #pragma unroll
    for (int f=0; f<8; ++f){
      const int slot = ((f*2 + lhi) ^ pm15) * 8;
      bf16x8 pf = *(const bf16x8*)&Ps[(w*32 + l31)*128 + slot];
      bf16x8 v0 = *(const bf16x8*)&Vs[l31*128 + slot];
      bf16x8 v1 = *(const bf16x8*)&Vs[(32 + l31)*128 + slot];
      lacc = __builtin_amdgcn_mfma_f32_32x32x16_bf16(pf, ones, lacc, 0,0,0);
      o0 = __builtin_amdgcn_mfma_f32_32x32x16_bf16(pf, v0, o0, 0,0,0);
      o1 = __builtin_amdgcn_mfma_f32_32x32x16_bf16(pf, v1, o1, 0,0,0);
    }
  }

  // ---- epilogue ----
  const int c0 = h*64 + l31;
  #pragma unroll
  for (int reg=0; reg<16; ++reg){
    float inv = 1.0f / lacc[reg];
    int qrm = (reg&3) + 8*(reg>>2) + 4*lhi;
    size_t row = (size_t)(qrow0 + w*32 + qrm);
    outp[row*256 + c0]      = f2bf(o0[reg] * inv);
    outp[row*256 + c0 + 32] = f2bf(o1[reg] * inv);
  }
}

// ---------------------------------------------------------------------------
// LayerNorm + exact GELU, one wave per 512-wide row, bf16 in/out
// ---------------------------------------------------------------------------
__global__ __launch_bounds__(256) void lngelu_k(const uint16_t* __restrict__ hpre,
                                                const float* __restrict__ g,
                                                const float* __restrict__ bb,
                                                uint16_t* __restrict__ h){
  const int row = blockIdx.x*4 + (threadIdx.x >> 6);
  const int l = threadIdx.x & 63;
  const uint16_t* rp = hpre + (size_t)row*512 + l*8;
  uint4 raw = *(const uint4*)rp;
  uint32_t wv[4] = {raw.x, raw.y, raw.z, raw.w};
  float x[8];
  #pragma unroll
  for (int j=0;j<4;++j){
    x[2*j]   = bf2f((uint16_t)(wv[j] & 0xFFFFu));
    x[2*j+1] = bf2f((uint16_t)(wv[j] >> 16));
  }
  float s = 0.f;
  #pragma unroll
  for (int j=0;j<8;++j) s += x[j];
  #pragma unroll
  for (int off=1; off<64; off<<=1) s += __shfl_xor(s, off, 64);
  float mu = s * (1.0f/512.0f);
  float vs = 0.f;
  #pragma unroll
  for (int j=0;j<8;++j){ float d = x[j]-mu; vs += d*d; }
  #pragma unroll
  for (int off=1; off<64; off<<=1) vs += __shfl_xor(vs, off, 64);
  float rstd = rsqrtf(vs*(1.0f/512.0f) + 1e-5f);
  const float* gp = g + l*8;
  const float* bp = bb + l*8;
  uint32_t ow[4];
  #pragma unroll
  for (int j=0;j<4;++j){
    float y0 = (x[2*j]-mu)*rstd*gp[2*j] + bp[2*j];
    float y1 = (x[2*j+1]-mu)*rstd*gp[2*j+1] + bp[2*j+1];
    float g0 = 0.5f*y0*(1.0f + erff(y0*0.70710678118f));
    float g1 = 0.5f*y1*(1.0f + erff(y1*0.70710678118f));
    ow[j] = (uint32_t)f2bf(g0) | ((uint32_t)f2bf(g1) << 16);
  }
  uint4 out4 = {ow[0], ow[1], ow[2], ow[3]};
  *(uint4*)(h + (size_t)row*512 + l*8) = out4;
}

// ---------------------------------------------------------------------------
extern "C" void kernel_launch(void* const* d_in, const int* in_sizes, int n_in,
                              void* d_out, int out_size, void* d_ws, size_t ws_size,
                              hipStream_t stream){
  (void)in_sizes; (void)n_in; (void)out_size; (void)ws_size;
  const float* x0   = (const float*)d_in[0];
  const float* x1   = (const float*)d_in[1];
  const float* w_qk = (const float*)d_in[2];
  const float* b_qk = (const float*)d_in[3];
  const float* w_v  = (const float*)d_in[4];
  const float* b_v  = (const float*)d_in[5];
  const float* w_out= (const float*)d_in[6];
  const float* b_out= (const float*)d_in[7];
  const float* w_f1 = (const float*)d_in[8];
  const float* b_f1 = (const float*)d_in[9];
  const float* ln_g = (const float*)d_in[10];
  const float* ln_b = (const float*)d_in[11];
  const float* w_f2 = (const float*)d_in[12];
  const float* b_f2 = (const float*)d_in[13];

  char* ws = (char*)d_ws;
  uint16_t* xb    = (uint16_t*)(ws);              //  8,388,608 B  [x0b | x1b]
  uint16_t* wqkT  = (uint16_t*)(ws +  8388608);
  uint16_t* wvT   = (uint16_t*)(ws +  8519680);
  uint16_t* woutT = (uint16_t*)(ws +  8650752);
  uint16_t* wf1T  = (uint16_t*)(ws +  8781824);
  uint16_t* wf2T  = (uint16_t*)(ws +  9306112);
  uint16_t* qk0b  = (uint16_t*)(ws +  9568256);
  uint16_t* qk1b  = (uint16_t*)(ws + 13762560);
  uint16_t* vt0b  = (uint16_t*)(ws + 17956864);
  uint16_t* vt1b  = (uint16_t*)(ws + 22151168);
  uint16_t* m0b   = (uint16_t*)(ws + 26345472);
  uint16_t* m1b   = (uint16_t*)(ws + 30539776);
  uint16_t* mp0b  = (uint16_t*)(ws + 34734080);
  uint16_t* mp1b  = (uint16_t*)(ws + 38928384);
  // aliases over dead buffers:
  uint16_t* hpreb = qk0b;   // [2][8192][512] bf16 over qk0..vt1 (dead after flash)
  uint16_t* hb    = m0b;    // [2][8192][512] bf16 over m0..mp1 (dead after ffn1)

  conv_all_k<<<dim3(2048,1,7), 256, 0, stream>>>(x0, x1, xb,
      w_qk, w_v, w_out, w_f1, w_f2, wqkT, wvT, woutT, wf1T, wf2T);

  GemmArgs g0 = {};
  g0.A0 = xb; g0.A1 = xb + 2097152;
  g0.Wt0 = wqkT; g0.Wt1 = wvT;
  g0.bias0 = b_qk; g0.bias1 = b_v;
  g0.out0 = qk0b; g0.out1 = qk1b; g0.out2 = vt0b; g0.out3 = vt1b;
  g0.K = 256;
  gemm_k<0><<<dim3(128,2,4), 256, 0, stream>>>(g0);

  flash_k<<<dim3(32,16,2), 128, 0, stream>>>(qk0b, qk1b, vt0b, vt1b, m0b, m1b);

  GemmArgs g1 = {};
  g1.A0 = m0b; g1.A1 = m1b;
  g1.Wt0 = woutT; g1.bias0 = b_out;
  g1.out0 = mp0b; g1.out1 = mp1b;
  g1.K = 256;
  gemm_k<1><<<dim3(128,2,2), 256, 0, stream>>>(g1);

  GemmArgs g2 = {};
  g2.A0 = xb; g2.A1 = xb + 2097152;
  g2.A2_0 = mp0b; g2.A2_1 = mp1b;
  g2.Wt0 = wf1T; g2.bias0 = b_f1;
  g2.out0 = hpreb; g2.out1 = hpreb + 4194304;
  g2.K = 512;
  gemm_k<2><<<dim3(128,4,2), 256, 0, stream>>>(g2);

  lngelu_k<<<dim3(4096,1,1), 256, 0, stream>>>(hpreb, ln_g, ln_b, hb);

  GemmArgs g3 = {};
  g3.A0 = hb; g3.A1 = hb + 4194304;
  g3.Wt0 = wf2T; g3.bias0 = b_f2;
  g3.fout = (float*)d_out;
  g3.xf0 = x0; g3.xf1 = x1;
  g3.K = 512;
  gemm_k<3><<<dim3(128,2,2), 256, 0, stream>>>(g3);
}

// Round 9
// 224.047 us; speedup vs baseline: 1.3376x; 1.1075x over previous
//
#include <hip/hip_runtime.h>
#include <cstdint>
#include <cstddef>

// ---------------------------------------------------------------------------
// CrossTransformer on MI355X.  B=4, N=2048, D=256, H=4, DH=64.
// R9: flash = R6's verified LDS staging (K/V tiles, XOR swizzle) + R7's
//     verified register P-transform (S^T = K.Q^T, lane owns a q-row,
//     P B-frags via 8 ds_bpermute(l^32) + packs).  Deletes per wave-iter:
//     32 ds_write_b16 + 4 b128 P-reads + 4 ones-MFMAs (l = in-lane scalar
//     sum of truncated p, one shfl at end).  LDS 16KB, grid (32,16,2)x128.
//     R8 verdict: wall is LDS-pipe-hottest multi-pipe saturation; drain
//     count not binding; occupancy must stay >= 8 waves/CU.
// GEMMs: exact R4 config (best non-flash 153us).  Converts merged (R8).
// ---------------------------------------------------------------------------

#define QKS2 0.4246609001440095f   // (DH^-0.25) * sqrt(log2(e))

typedef short bf16x8 __attribute__((ext_vector_type(8)));
typedef float f32x4  __attribute__((ext_vector_type(4)));
typedef float f32x16 __attribute__((ext_vector_type(16)));

__device__ __forceinline__ uint16_t f2bf(float f){
  union { float f; uint32_t u; } v; v.f = f;
  uint32_t r = v.u + 0x7FFFu + ((v.u >> 16) & 1u);
  return (uint16_t)(r >> 16);
}
__device__ __forceinline__ float bf2f(uint16_t h){
  union { uint32_t u; float f; } v; v.u = ((uint32_t)h) << 16; return v.f;
}
__device__ __forceinline__ uint32_t fbits(float f){
  union { float f; uint32_t u; } v; v.f = f; return v.u;
}
__device__ __forceinline__ float bits2f(uint32_t u){
  union { uint32_t u; float f; } v; v.u = u; return v.f;
}
// pack two fp32 -> two bf16 (truncating): [lo16=trunc(a), hi16=trunc(b)]
__device__ __forceinline__ uint32_t pk2bf(float a, float b){
  return (fbits(b) & 0xFFFF0000u) | (fbits(a) >> 16);
}

// async global->LDS, 16B per lane; LDS dest = wave-uniform base + lane*16
__device__ __forceinline__ void gl_lds16(const void* g, void* l){
  void* g2 = const_cast<void*>(g);
  __builtin_amdgcn_global_load_lds((__attribute__((address_space(1))) void*)g2,
                                   (__attribute__((address_space(3))) void*)l,
                                   16, 0, 0);
}

// ---------------------------------------------------------------------------
// merged converts: z=0..4 -> weights [K][N] fp32 -> bf16 [N][K]; z=5,6 -> x
// ---------------------------------------------------------------------------
__global__ __launch_bounds__(256) void conv_all_k(
    const float* __restrict__ x0, const float* __restrict__ x1,
    uint16_t* __restrict__ xb,
    const float* w0, const float* w1, const float* w2, const float* w3, const float* w4,
    uint16_t* t0, uint16_t* t1, uint16_t* t2, uint16_t* t3, uint16_t* t4){
  const int z = blockIdx.z;
  if (z >= 5){
    const float* src = (z == 6) ? x1 : x0;
    uint16_t* dst = xb + (size_t)(z - 5) * 2097152;
    size_t i = ((size_t)blockIdx.x * 256 + threadIdx.x) * 4;
    float4 v = *(const float4*)(src + i);
    uint2 o;
    o.x = (uint32_t)f2bf(v.x) | ((uint32_t)f2bf(v.y) << 16);
    o.y = (uint32_t)f2bf(v.z) | ((uint32_t)f2bf(v.w) << 16);
    *(uint2*)(dst + i) = o;
    return;
  }
  const float* src = z==0? w0 : z==1? w1 : z==2? w2 : z==3? w3 : w4;
  uint16_t*   dst  = z==0? t0 : z==1? t1 : z==2? t2 : z==3? t3 : t4;
  const int K = (z>=3)? 512 : 256;
  const int N = (z==3)? 512 : 256;
  int idx = blockIdx.x * 256 + threadIdx.x;
  if (idx >= (K*N)/4) return;
  int k = idx / (N/4);
  int n = (idx % (N/4)) * 4;
  float4 v = *(const float4*)(src + (size_t)k*N + n);
  dst[(size_t)(n+0)*K + k] = f2bf(v.x);
  dst[(size_t)(n+1)*K + k] = f2bf(v.y);
  dst[(size_t)(n+2)*K + k] = f2bf(v.z);
  dst[(size_t)(n+3)*K + k] = f2bf(v.w);
}

// ---------------------------------------------------------------------------
// unified GEMM  C[M=8192, N] = A[M,K](bf16) * W[K,N] + bias, epilogue by MODE
// Tile 64(M) x 128(N), BK=64.  4 waves, each 64x32 (acc 4x2).   (R4 config)
// LDS tiles chunk-swizzled: (row r, 8-elem chunk c) at slot c^(r&7).
// ---------------------------------------------------------------------------
struct GemmArgs {
  const uint16_t* A0; const uint16_t* A1;
  const uint16_t* A2_0; const uint16_t* A2_1;
  const uint16_t* Wt0; const uint16_t* Wt1;
  const float* bias0; const float* bias1;
  uint16_t* out0; uint16_t* out1; uint16_t* out2; uint16_t* out3;
  float* fout; const float* xf0; const float* xf1;
  int K;
};

template<int MODE>
__global__ __launch_bounds__(256, 4) void gemm_k(GemmArgs a){
  __shared__ __align__(16) uint16_t As[64*64];
  __shared__ __align__(16) uint16_t Bs[128*64];
  const int tid = threadIdx.x;
  const int w = tid >> 6, l = tid & 63;
  const int z = blockIdx.z;
  const int which = (MODE==0) ? (z & 1) : z;
  const int wsel  = (MODE==0) ? (z >> 1) : 0;
  const int K = a.K;
  const int m0 = blockIdx.x * 64;
  const int n0 = blockIdx.y * 128;
  const uint16_t* Wt   = wsel ? a.Wt1 : a.Wt0;
  const float* bias    = wsel ? a.bias1 : a.bias0;
  const uint16_t* Ab   = which ? a.A1 : a.A0;
  const uint16_t* Ab2  = which ? a.A2_1 : a.A2_0;

  f32x4 acc[4][2];
  #pragma unroll
  for (int i=0;i<4;++i)
    #pragma unroll
    for (int j=0;j<2;++j) acc[i][j] = (f32x4){0.f,0.f,0.f,0.f};

  const int lrow8 = l >> 3, lch = l & 7;
  const int swch = (lch ^ lrow8) * 8;          // swizzled source chunk offset
  const int quad = l >> 4, l15 = l & 15, h7 = l15 & 7;

  for (int k0 = 0; k0 < K; k0 += 64){
    __syncthreads();
    const uint16_t* Asrc; int lda;
    if (MODE == 2){
      Asrc = (k0 < 256) ? (Ab + k0) : (Ab2 + (k0 - 256));
      lda = 256;
    } else { Asrc = Ab + k0; lda = K; }
    #pragma unroll
    for (int j=0;j<2;++j){
      int wi = w*2 + j;                    // 0..7
      int row = wi*8 + lrow8;              // 0..63
      gl_lds16(Asrc + (size_t)(m0 + row)*lda + swch, &As[wi*512]);
    }
    #pragma unroll
    for (int j=0;j<4;++j){
      int wi = w*4 + j;                    // 0..15
      int row = wi*8 + lrow8;              // 0..127
      gl_lds16(Wt + (size_t)(n0 + row)*K + k0 + swch, &Bs[wi*512]);
    }
    __syncthreads();
    #pragma unroll
    for (int kc=0;kc<2;++kc){
      const int fch = ((kc*4 + quad) ^ h7) * 8;  // swizzled fragment chunk
      bf16x8 af[4], bfr[2];
      #pragma unroll
      for (int rt=0;rt<4;++rt)
        af[rt] = *(const bf16x8*)&As[(rt*16 + l15)*64 + fch];
      #pragma unroll
      for (int ct=0;ct<2;++ct)
        bfr[ct] = *(const bf16x8*)&Bs[(w*32 + ct*16 + l15)*64 + fch];
      #pragma unroll
      for (int rt=0;rt<4;++rt)
        #pragma unroll
        for (int ct=0;ct<2;++ct)
          acc[rt][ct] = __builtin_amdgcn_mfma_f32_16x16x32_bf16(af[rt], bfr[ct], acc[rt][ct], 0,0,0);
    }
  }

  // epilogue (C layout: col = lane&15, row = (lane>>4)*4 + reg)
  #pragma unroll
  for (int rt=0;rt<4;++rt){
    const int r0 = m0 + rt*16 + (quad<<2);
    #pragma unroll
    for (int ct=0;ct<2;++ct){
      const int c = n0 + w*32 + ct*16 + l15;
      const float bv = bias[c];
      if (MODE == 0){
        if (wsel == 0){
          uint16_t* q = which ? a.out1 : a.out0;
          #pragma unroll
          for (int i=0;i<4;++i)
            q[(size_t)(r0+i)*256 + c] = f2bf((acc[rt][ct][i] + bv) * QKS2);
        } else {
          uint16_t* vt = which ? a.out3 : a.out2;
          const int bb = r0 >> 11, nn = r0 & 2047;
          const int hh = c >> 6,  dd = c & 63;
          uint2 pk;
          pk.x = (uint32_t)f2bf(acc[rt][ct][0] + bv) | ((uint32_t)f2bf(acc[rt][ct][1] + bv) << 16);
          pk.y = (uint32_t)f2bf(acc[rt][ct][2] + bv) | ((uint32_t)f2bf(acc[rt][ct][3] + bv) << 16);
          *(uint2*)(vt + ((size_t)((bb*4 + hh)*64 + dd))*2048 + nn) = pk;
        }
      } else if (MODE == 1){
        uint16_t* o = which ? a.out1 : a.out0;
        #pragma unroll
        for (int i=0;i<4;++i)
          o[(size_t)(r0+i)*256 + c] = f2bf(acc[rt][ct][i] + bv);
      } else if (MODE == 2){
        uint16_t* o = which ? a.out1 : a.out0;
        #pragma unroll
        for (int i=0;i<4;++i)
          o[(size_t)(r0+i)*512 + c] = f2bf(acc[rt][ct][i] + bv);
      } else {
        const float* xf = which ? a.xf1 : a.xf0;
        float* fo = a.fout + (size_t)which * 2097152;
        #pragma unroll
        for (int i=0;i<4;++i)
          fo[(size_t)(r0+i)*256 + c] = acc[rt][ct][i] + bv + xf[(size_t)(r0+i)*256 + c];
      }
    }
  }
}

// ---------------------------------------------------------------------------
// flash attention: LDS-staged K/V + register-space P transform.
// Q tile 64 = 2 waves x 32 q-rows; K tile 64; grid (32,16,2), 128 threads.
// S^T = K.Q^T (A = K rows from LDS, B = Q^T regs); C-layout col = lane&31 =
// q-row (lane owns a full q-row).  p = exp2(s) (fixed-max; shift cancels).
// P^T B-frags: 8 ds_bpermute(l^32) + packs [R7-verified].  l = in-lane sum
// of truncated p + one shfl_xor(32) at the end.  O^T = V^T.P^T.
// LDS: Ks 8K + Vs 8K = 16KB.  Swizzle slot = c ^ (r&7) ^ ((r>>3)&7) [R6-ver].
// ---------------------------------------------------------------------------
__global__ __launch_bounds__(128, 2) void flash_k(
    const uint16_t* __restrict__ qk0, const uint16_t* __restrict__ qk1,
    const uint16_t* __restrict__ vt0, const uint16_t* __restrict__ vt1,
    uint16_t* __restrict__ m0b, uint16_t* __restrict__ m1b){
  __shared__ __align__(16) uint16_t Ks[64*64];
  __shared__ __align__(16) uint16_t Vs[64*64];   // V^T tile [dout][key]
  const int tid = threadIdx.x;
  const int w = tid >> 6, l = tid & 63;          // w in {0,1}
  const int l31 = l & 31, lhi = l >> 5;
  const int rsub = l31 >> 3;
  const int lrow8 = l >> 3, lch8 = l & 7;
  const int qt = blockIdx.x;       // 0..31
  const int bh = blockIdx.y;       // 0..15  (b*4 + h)
  const int dir = blockIdx.z;
  const int b = bh >> 2, h = bh & 3;
  const uint16_t* Q   = dir ? qk1 : qk0;
  const uint16_t* Kg  = dir ? qk0 : qk1;
  const uint16_t* Vt  = dir ? vt0 : vt1;
  uint16_t* outp      = dir ? m1b : m0b;

  const int qrow0 = b*2048 + qt*64;
  const int pidx = (l ^ 32) << 2;                // bpermute partner index
  const bool hi = (lhi != 0);

  // ---- stage Q (64 rows x 64 d) into Ks, then read Q^T B-frags to regs ----
  #pragma unroll
  for (int j=0;j<4;++j){
    int g = w*4 + j;                             // 0..7
    int row = g*8 + lrow8;                       // 0..63
    int sc = lch8 ^ lrow8 ^ (g & 7);
    gl_lds16(Q + (size_t)(qrow0 + row)*256 + h*64 + sc*8, &Ks[g*512]);
  }
  __syncthreads();
  bf16x8 qf[4];
  {
    const int qmask = (l31 & 7) ^ (w*4 + rsub);  // row = w*32 + l31
    #pragma unroll
    for (int ks=0;ks<4;++ks)
      qf[ks] = *(const bf16x8*)&Ks[(w*32 + l31)*64 + (((ks*2 + lhi) ^ qmask))*8];
  }

  f32x16 o0, o1;
  #pragma unroll
  for (int i=0;i<16;++i){ o0[i]=0.f; o1[i]=0.f; }
  float lsum = 0.f;

  const size_t vbase = (size_t)bh * 131072;      // 64*2048
  const int vmask0 = (l31 & 7) ^ rsub;           // V rows douts 0..31
  const int vmask1 = (l31 & 7) ^ (4 + rsub);     // V rows douts 32..63

  for (int kt=0; kt<32; ++kt){
    __syncthreads();   // prior-iter readers done (also protects qf staging on iter 0)
    #pragma unroll
    for (int j=0;j<4;++j){
      int g = w*4 + j;                           // 0..7
      int row = g*8 + lrow8;                     // 0..63
      int sc = lch8 ^ lrow8 ^ (g & 7);
      gl_lds16(Kg + (size_t)(b*2048 + kt*64 + row)*256 + h*64 + sc*8, &Ks[g*512]);
      gl_lds16(Vt + vbase + (size_t)row*2048 + kt*64 + sc*8, &Vs[g*512]);
    }
    __syncthreads();

    // ---- S^T = K.Q^T : lane owns q-row l31 (wave-local); keys in regs ----
    f32x16 st0, st1;
    #pragma unroll
    for (int i=0;i<16;++i){ st0[i]=0.f; st1[i]=0.f; }
    #pragma unroll
    for (int ks=0;ks<4;++ks){
      const int ch = ks*2 + lhi;
      bf16x8 k0 = *(const bf16x8*)&Ks[l31*64        + ((ch ^ vmask0))*8];  // keys 0..31
      bf16x8 k1 = *(const bf16x8*)&Ks[(32 + l31)*64 + ((ch ^ vmask1))*8];  // keys 32..63
      st0 = __builtin_amdgcn_mfma_f32_32x32x16_bf16(k0, qf[ks], st0, 0,0,0);
      st1 = __builtin_amdgcn_mfma_f32_32x32x16_bf16(k1, qf[ks], st1, 0,0,0);
    }

    // ---- p = exp2(s); truncate; pack; in-lane l sum ----
    uint32_t pkA[2][4], pkB[2][4];     // [sblk][quad g]
    #pragma unroll
    for (int g=0; g<4; ++g){
      uint32_t a0 = fbits(__builtin_amdgcn_exp2f(st0[4*g+0])) & 0xFFFF0000u;
      uint32_t a1 = fbits(__builtin_amdgcn_exp2f(st0[4*g+1])) & 0xFFFF0000u;
      uint32_t a2 = fbits(__builtin_amdgcn_exp2f(st0[4*g+2])) & 0xFFFF0000u;
      uint32_t a3 = fbits(__builtin_amdgcn_exp2f(st0[4*g+3])) & 0xFFFF0000u;
      pkA[0][g] = a1 | (a0 >> 16);
      pkB[0][g] = a3 | (a2 >> 16);
      lsum += bits2f(a0) + bits2f(a1) + bits2f(a2) + bits2f(a3);
      uint32_t c0 = fbits(__builtin_amdgcn_exp2f(st1[4*g+0])) & 0xFFFF0000u;
      uint32_t c1 = fbits(__builtin_amdgcn_exp2f(st1[4*g+1])) & 0xFFFF0000u;
      uint32_t c2 = fbits(__builtin_amdgcn_exp2f(st1[4*g+2])) & 0xFFFF0000u;
      uint32_t c3 = fbits(__builtin_amdgcn_exp2f(st1[4*g+3])) & 0xFFFF0000u;
      pkA[1][g] = c1 | (c0 >> 16);
      pkB[1][g] = c3 | (c2 >> 16);
      lsum += bits2f(c0) + bits2f(c1) + bits2f(c2) + bits2f(c3);
    }

    // ---- P^T B-frags via partner exchange (lane l^32) [R7-verified] ----
    bf16x8 pfrag[4];
    #pragma unroll
    for (int f=0; f<4; ++f){
      const int sb = f >> 1, m2 = f & 1;
      uint32_t ownA0 = pkA[sb][2*m2],   ownB0 = pkB[sb][2*m2];
      uint32_t ownA1 = pkA[sb][2*m2+1], ownB1 = pkB[sb][2*m2+1];
      uint32_t tA = hi ? ownA0 : ownA1;
      uint32_t tB = hi ? ownB0 : ownB1;
      uint32_t rA = (uint32_t)__builtin_amdgcn_ds_bpermute(pidx, (int)tA);
      uint32_t rB = (uint32_t)__builtin_amdgcn_ds_bpermute(pidx, (int)tB);
      uint32_t v0 = hi ? rA : ownA0;
      uint32_t v1 = hi ? rB : ownB0;
      uint32_t v2 = hi ? ownA1 : rA;
      uint32_t v3 = hi ? ownB1 : rB;
      union { uint32_t u[4]; bf16x8 v; } cvt;
      cvt.u[0]=v0; cvt.u[1]=v1; cvt.u[2]=v2; cvt.u[3]=v3;
      pfrag[f] = cvt.v;
    }

    // ---- O^T += V^T.P^T ----
    #pragma unroll
    for (int f=0; f<4; ++f){
      const int ch = f*2 + lhi;
      bf16x8 v0 = *(const bf16x8*)&Vs[l31*64        + ((ch ^ vmask0))*8];
      bf16x8 v1 = *(const bf16x8*)&Vs[(32 + l31)*64 + ((ch ^ vmask1))*8];
      o0 = __builtin_amdgcn_mfma_f32_32x32x16_bf16(v0, pfrag[f], o0, 0,0,0);
      o1 = __builtin_amdgcn_mfma_f32_32x32x16_bf16(v1, pfrag[f], o1, 0,0,0);
    }
  }

  // ---- epilogue: lane owns q-row; O^T col = l31, rows = dout ----
  const float ltot = lsum + __shfl_xor(lsum, 32);
  const float inv = 1.0f / ltot;
  const int qrow = qrow0 + w*32 + l31;
  uint16_t* op = outp + (size_t)qrow*256 + h*64 + lhi*4;
  #pragma unroll
  for (int g=0; g<4; ++g){
    uint32_t p01 = (uint32_t)f2bf(o0[4*g+0]*inv) | ((uint32_t)f2bf(o0[4*g+1]*inv) << 16);
    uint32_t p23 = (uint32_t)f2bf(o0[4*g+2]*inv) | ((uint32_t)f2bf(o0[4*g+3]*inv) << 16);
    *(uint2*)(op + 8*g) = (uint2){p01, p23};
    uint32_t q01 = (uint32_t)f2bf(o1[4*g+0]*inv) | ((uint32_t)f2bf(o1[4*g+1]*inv) << 16);
    uint32_t q23 = (uint32_t)f2bf(o1[4*g+2]*inv) | ((uint32_t)f2bf(o1[4*g+3]*inv) << 16);
    *(uint2*)(op + 32 + 8*g) = (uint2){q01, q23};
  }
}

// ---------------------------------------------------------------------------
// LayerNorm + exact GELU, one wave per 512-wide row, bf16 in/out
// ---------------------------------------------------------------------------
__global__ __launch_bounds__(256) void lngelu_k(const uint16_t* __restrict__ hpre,
                                                const float* __restrict__ g,
                                                const float* __restrict__ bb,
                                                uint16_t* __restrict__ h){
  const int row = blockIdx.x*4 + (threadIdx.x >> 6);
  const int l = threadIdx.x & 63;
  const uint16_t* rp = hpre + (size_t)row*512 + l*8;
  uint4 raw = *(const uint4*)rp;
  uint32_t wv[4] = {raw.x, raw.y, raw.z, raw.w};
  float x[8];
  #pragma unroll
  for (int j=0;j<4;++j){
    x[2*j]   = bf2f((uint16_t)(wv[j] & 0xFFFFu));
    x[2*j+1] = bf2f((uint16_t)(wv[j] >> 16));
  }
  float s = 0.f;
  #pragma unroll
  for (int j=0;j<8;++j) s += x[j];
  #pragma unroll
  for (int off=1; off<64; off<<=1) s += __shfl_xor(s, off, 64);
  float mu = s * (1.0f/512.0f);
  float vs = 0.f;
  #pragma unroll
  for (int j=0;j<8;++j){ float d = x[j]-mu; vs += d*d; }
  #pragma unroll
  for (int off=1; off<64; off<<=1) vs += __shfl_xor(vs, off, 64);
  float rstd = rsqrtf(vs*(1.0f/512.0f) + 1e-5f);
  const float* gp = g + l*8;
  const float* bp = bb + l*8;
  uint32_t ow[4];
  #pragma unroll
  for (int j=0;j<4;++j){
    float y0 = (x[2*j]-mu)*rstd*gp[2*j] + bp[2*j];
    float y1 = (x[2*j+1]-mu)*rstd*gp[2*j+1] + bp[2*j+1];
    float g0 = 0.5f*y0*(1.0f + erff(y0*0.70710678118f));
    float g1 = 0.5f*y1*(1.0f + erff(y1*0.70710678118f));
    ow[j] = (uint32_t)f2bf(g0) | ((uint32_t)f2bf(g1) << 16);
  }
  uint4 out4 = {ow[0], ow[1], ow[2], ow[3]};
  *(uint4*)(h + (size_t)row*512 + l*8) = out4;
}

// ---------------------------------------------------------------------------
extern "C" void kernel_launch(void* const* d_in, const int* in_sizes, int n_in,
                              void* d_out, int out_size, void* d_ws, size_t ws_size,
                              hipStream_t stream){
  (void)in_sizes; (void)n_in; (void)out_size; (void)ws_size;
  const float* x0   = (const float*)d_in[0];
  const float* x1   = (const float*)d_in[1];
  const float* w_qk = (const float*)d_in[2];
  const float* b_qk = (const float*)d_in[3];
  const float* w_v  = (const float*)d_in[4];
  const float* b_v  = (const float*)d_in[5];
  const float* w_out= (const float*)d_in[6];
  const float* b_out= (const float*)d_in[7];
  const float* w_f1 = (const float*)d_in[8];
  const float* b_f1 = (const float*)d_in[9];
  const float* ln_g = (const float*)d_in[10];
  const float* ln_b = (const float*)d_in[11];
  const float* w_f2 = (const float*)d_in[12];
  const float* b_f2 = (const float*)d_in[13];

  char* ws = (char*)d_ws;
  uint16_t* xb    = (uint16_t*)(ws);              //  8,388,608 B  [x0b | x1b]
  uint16_t* wqkT  = (uint16_t*)(ws +  8388608);
  uint16_t* wvT   = (uint16_t*)(ws +  8519680);
  uint16_t* woutT = (uint16_t*)(ws +  8650752);
  uint16_t* wf1T  = (uint16_t*)(ws +  8781824);
  uint16_t* wf2T  = (uint16_t*)(ws +  9306112);
  uint16_t* qk0b  = (uint16_t*)(ws +  9568256);
  uint16_t* qk1b  = (uint16_t*)(ws + 13762560);
  uint16_t* vt0b  = (uint16_t*)(ws + 17956864);
  uint16_t* vt1b  = (uint16_t*)(ws + 22151168);
  uint16_t* m0b   = (uint16_t*)(ws + 26345472);
  uint16_t* m1b   = (uint16_t*)(ws + 30539776);
  uint16_t* mp0b  = (uint16_t*)(ws + 34734080);
  uint16_t* mp1b  = (uint16_t*)(ws + 38928384);
  // aliases over dead buffers:
  uint16_t* hpreb = qk0b;   // [2][8192][512] bf16 over qk0..vt1 (dead after flash)
  uint16_t* hb    = m0b;    // [2][8192][512] bf16 over m0..mp1 (dead after ffn1)

  conv_all_k<<<dim3(2048,1,7), 256, 0, stream>>>(x0, x1, xb,
      w_qk, w_v, w_out, w_f1, w_f2, wqkT, wvT, woutT, wf1T, wf2T);

  GemmArgs g0 = {};
  g0.A0 = xb; g0.A1 = xb + 2097152;
  g0.Wt0 = wqkT; g0.Wt1 = wvT;
  g0.bias0 = b_qk; g0.bias1 = b_v;
  g0.out0 = qk0b; g0.out1 = qk1b; g0.out2 = vt0b; g0.out3 = vt1b;
  g0.K = 256;
  gemm_k<0><<<dim3(128,2,4), 256, 0, stream>>>(g0);

  flash_k<<<dim3(32,16,2), 128, 0, stream>>>(qk0b, qk1b, vt0b, vt1b, m0b, m1b);

  GemmArgs g1 = {};
  g1.A0 = m0b; g1.A1 = m1b;
  g1.Wt0 = woutT; g1.bias0 = b_out;
  g1.out0 = mp0b; g1.out1 = mp1b;
  g1.K = 256;
  gemm_k<1><<<dim3(128,2,2), 256, 0, stream>>>(g1);

  GemmArgs g2 = {};
  g2.A0 = xb; g2.A1 = xb + 2097152;
  g2.A2_0 = mp0b; g2.A2_1 = mp1b;
  g2.Wt0 = wf1T; g2.bias0 = b_f1;
  g2.out0 = hpreb; g2.out1 = hpreb + 4194304;
  g2.K = 512;
  gemm_k<2><<<dim3(128,4,2), 256, 0, stream>>>(g2);

  lngelu_k<<<dim3(4096,1,1), 256, 0, stream>>>(hpreb, ln_g, ln_b, hb);

  GemmArgs g3 = {};
  g3.A0 = hb; g3.A1 = hb + 4194304;
  g3.Wt0 = wf2T; g3.bias0 = b_f2;
  g3.fout = (float*)d_out;
  g3.xf0 = x0; g3.xf1 = x1;
  g3.K = 512;
  gemm_k<3><<<dim3(128,2,2), 256, 0, stream>>>(g3);
}